// Round 3
// baseline (370.754 us; speedup 1.0000x reference)
//
#include <hip/hip_runtime.h>
#include <math.h>

#ifndef M_PI
#define M_PI 3.14159265358979323846
#endif

constexpr int S_LEN    = 176400;
constexpr int NFFT     = 2048;
constexpr int NC       = 1024;
constexpr int HOP_     = 441;
constexpr int T_FRAMES = 401;
constexpr int F_BINS   = 1025;
constexpr int F_STRIDE = 1028;     // fp32 spec row stride (16B aligned)
constexpr int N_CH     = 64;
constexpr float EPS_   = 1e-8f;
constexpr float C1_    = 0.0004f;
constexpr float C2_    = 0.0036f;
constexpr float COV_NORM_ = 49.0f / 48.0f;

// workspace float offsets
constexpr int WIN_OFF  = 0;        // float[2048] hann window
constexpr int TWG_OFF  = 2048;     // float2[768]  tw[e] = exp(-2pi i e/1024)
constexpr int UTW_OFF  = 3584;     // float2[1025] exp(-i pi r/1024)
constexpr int SPEC_OFF = 5696;

// ssim wave decomposition: 5 column bands x 25 row chunks per channel
constexpr int ROWS_PW   = 16;
constexpr int NCHUNKS_R = 25;      // ceil(395/16)
constexpr int BANDS     = 5;
constexpr int BAND_ADV  = 248;     // 62 producing lanes * 4 cols

// LDS bank swizzle: phys(i) = i ^ ((i>>2)&15) ^ ((i>>6)&15).
// Triangular in GF(2) (bits0-3 ^= f(bits2-9)) -> bijective on [0,1024).
// Conflict-checked per pattern (16 consecutive lanes -> 16 distinct low-nibbles).
__device__ __forceinline__ int phys(int i) { return i ^ ((i >> 2) & 15) ^ ((i >> 6) & 15); }

__device__ __forceinline__ float2 cadd(float2 a, float2 b){ return make_float2(a.x+b.x, a.y+b.y); }
__device__ __forceinline__ float2 csub(float2 a, float2 b){ return make_float2(a.x-b.x, a.y-b.y); }
__device__ __forceinline__ float2 cmul(float2 a, float2 b){ return make_float2(a.x*b.x-a.y*b.y, a.x*b.y+a.y*b.x); }

__global__ __launch_bounds__(256) void init_tables_kernel(float* __restrict__ ws, float* __restrict__ out) {
    const int idx = blockIdx.x * 256 + threadIdx.x;
    if (idx < 64) out[idx] = 0.0f;
    if (idx < NFFT) {
        ws[WIN_OFF + idx] = 0.5f - 0.5f * cosf((float)(2.0 * M_PI / NFFT) * (float)idx);
    }
    if (idx < 768) {
        float ang = -2.0f * (float)M_PI * (float)idx / (float)NC;
        float s, c; sincosf(ang, &s, &c);
        ws[TWG_OFF + 2*idx] = c; ws[TWG_OFF + 2*idx+1] = s;
    }
    if (idx < F_BINS) {
        float ang = -(float)M_PI * (float)idx / (float)NC;
        float s, c; sincosf(ang, &s, &c);
        ws[UTW_OFF + 2*idx] = c; ws[UTW_OFF + 2*idx+1] = s;
    }
}

// In-place radix-4 DIF butterfly: reads 4 LDS slots, writes SAME 4 slots.
__device__ __forceinline__ void r4_dif_inplace(
    float2* __restrict__ A, int r0, int r1, int r2, int r3,
    float2 w1, float2 w2, float2 w3, bool tw)
{
    float2 x0c = A[r0];
    float2 x1c = A[r1];
    float2 x2c = A[r2];
    float2 x3c = A[r3];

    float2 a = cadd(x0c, x2c);
    float2 b = csub(x0c, x2c);
    float2 c = cadd(x1c, x3c);
    float2 d = csub(x1c, x3c);

    float2 y0 = cadd(a, c);
    float2 y2 = csub(a, c);
    float2 y1 = make_float2(b.x + d.y, b.y - d.x);   // b - i*d
    float2 y3 = make_float2(b.x - d.y, b.y + d.x);   // b + i*d

    A[r0] = y0;
    A[r1] = tw ? cmul(y1, w1) : y1;
    A[r2] = tw ? cmul(y2, w2) : y2;
    A[r3] = tw ? cmul(y3, w3) : y3;
}

// Block-wide DUAL 1024-pt complex radix-4 IN-PLACE DIF (unchanged from R2:
// 194.8us, VALU 77%, occ 81%).
__global__ __launch_bounds__(256, 8) void stft_mag_kernel(
    const float* __restrict__ x0, const float* __restrict__ x1,
    float* __restrict__ ws, int ch0, int nch, int swizzle)
{
    __shared__ float2 buf[2 * NC];   // FFT0 at [0,NC), FFT1 at [NC,2NC)

    const int tid = threadIdx.x;

    int ch, t;
    if (swizzle) {
        int g = blockIdx.x;
        ch = ch0 + (g & 7) * 8 + ((g >> 3) & 7);
        t  = g >> 6;
    } else {
        t  = blockIdx.x;
        ch = ch0 + blockIdx.y;
    }

    const float* __restrict__ xin0 = x0 + (size_t)ch * S_LEN;
    const float* __restrict__ xin1 = x1 + (size_t)ch * S_LEN;
    const float*  __restrict__ win = ws + WIN_OFF;
    const float2* __restrict__ twg = (const float2*)(ws + TWG_OFF);
    const float2* __restrict__ utw = (const float2*)(ws + UTW_OFF);

    // ---- pack: flat float index n over [0,2048); complex ci = n>>1 (swizzled)
    const int base = t * HOP_ - NFFT / 2;
    float* fA0 = (float*)buf;             // FFT0
    float* fA1 = (float*)(buf + NC);      // FFT1 (+8 KB)
    if (base >= 0 && base + NFFT <= S_LEN) {
        #pragma unroll
        for (int k = 0; k < NFFT / 256; ++k) {
            int n = k * 256 + tid;
            int j = base + n;
            float w = win[n];
            int p = 2 * phys(n >> 1) + (n & 1);
            fA0[p] = xin0[j] * w;
            fA1[p] = xin1[j] * w;
        }
    } else {
        #pragma unroll
        for (int k = 0; k < NFFT / 256; ++k) {
            int n = k * 256 + tid;
            int j = base + n;
            j = (j < 0) ? -j : j;
            j = (j >= S_LEN) ? (2 * S_LEN - 2 - j) : j;
            float w = win[n];
            int p = 2 * phys(n >> 1) + (n & 1);
            fA0[p] = xin0[j] * w;
            fA1[p] = xin1[j] * w;
        }
    }
    __syncthreads();

    // ---- 5-stage in-place radix-4 DIF, x2 FFTs
    #pragma unroll
    for (int s = 0; s < 5; ++s) {
        const int M  = 256 >> (2 * s);
        const int q  = tid & (M - 1);
        const int e  = q << (2 * s);
        const int i0 = 4 * (tid - q) + q;

        const int r0 = phys(i0);
        const int r1 = phys(i0 + M);
        const int r2 = phys(i0 + 2 * M);
        const int r3 = phys(i0 + 3 * M);

        float2 w1, w2, w3;
        if (s < 4) {
            w1 = twg[e];
            w2 = twg[2 * e];
            w3 = twg[3 * e];
        } else {
            w1 = w2 = w3 = make_float2(1.0f, 0.0f);
        }

        r4_dif_inplace(buf,      r0, r1, r2, r3, w1, w2, w3, s < 4);
        r4_dif_inplace(buf + NC, r0, r1, r2, r3, w1, w2, w3, s < 4);

        __syncthreads();
    }

    // ---- real-FFT unpack + magnitude + fp32 coalesced stores (both tensors)
    const size_t perT = (size_t)T_FRAMES * F_STRIDE;
    float* __restrict__ sout0 =
        ws + SPEC_OFF + (size_t)(ch - ch0) * perT + (size_t)t * F_STRIDE;
    float* __restrict__ sout1 = sout0 + (size_t)nch * perT;

    const int R8 = ((tid & 3) << 6) | ((tid & 12) << 2) | ((tid >> 2) & 12) | ((tid >> 6) & 3);

    #pragma unroll
    for (int k = 0; k < 5; ++k) {
        int r = k * 256 + tid;
        if (k < 4 || tid == 0) {
            const int ra = (k < 4) ? ((R8 << 2) | k) : 0;          // rev4(r & 1023)
            const int rn = (NC - r) & (NC - 1);
            const int rb = ((rn & 3) << 8) | ((rn & 12) << 4) | (rn & 48)
                         | ((rn >> 4) & 12) | ((rn >> 8) & 3);     // rev4(rn)
            const int ia = phys(ra);
            const int ib = phys(rb);
            float2 wu = utw[r];

            {   // tensor 0
                float2 Zr = buf[ia];
                float2 Zn = buf[ib];
                float Ex = 0.5f * (Zr.x + Zn.x);
                float Ey = 0.5f * (Zr.y - Zn.y);
                float Ox = 0.5f * (Zr.y + Zn.y);
                float Oy = 0.5f * (Zn.x - Zr.x);
                float Xx = Ex + wu.x * Ox - wu.y * Oy;
                float Xy = Ey + wu.x * Oy + wu.y * Ox;
                sout0[r] = sqrtf(fmaxf(Xx * Xx + Xy * Xy, EPS_));
            }
            {   // tensor 1
                float2 Zr = buf[NC + ia];
                float2 Zn = buf[NC + ib];
                float Ex = 0.5f * (Zr.x + Zn.x);
                float Ey = 0.5f * (Zr.y - Zn.y);
                float Ox = 0.5f * (Zr.y + Zn.y);
                float Oy = 0.5f * (Zn.x - Zr.x);
                float Xx = Ex + wu.x * Ox - wu.y * Oy;
                float Xy = Ey + wu.x * Oy + wu.y * Ox;
                sout1[r] = sqrtf(fmaxf(Xx * Xx + Xy * Xy, EPS_));
            }
        }
    }
}

// SSIM v2: barrier-free, LDS-free, wave-independent.
// Each 64-lane wave owns (channel, column-band, row-chunk).  Lane L holds the
// vertical rolling 7-row sums of 4 columns in registers; the horizontal 7-wide
// window is assembled from per-lane prefix sums + neighbor-lane prefixes via
// __shfl_down (+1, +2 lanes).  Lanes 62/63 (and over-edge lanes of band 4)
// compute garbage that is provably confined to discarded (guarded) outputs.
// Bands: b=0..4 start at input col 248*b; producing lanes 0..61 -> output cols
// [248b+3, 248b+250]; coverage of [3,1021] is disjoint and complete.
#define HWIN7(sarr, W) {                                                     \
    float p0 = sarr[0], p01 = p0 + sarr[1], p012 = p01 + sarr[2],            \
          P = p012 + sarr[3];                                                \
    float a1 = __shfl_down(p012, 1, 64);                                     \
    float A1 = __shfl_down(P,    1, 64);                                     \
    float b0 = __shfl_down(p0,   2, 64);                                     \
    float b1 = __shfl_down(p01,  2, 64);                                     \
    W[0] = P + a1;                                                           \
    W[1] = P - p0 + A1;                                                      \
    W[2] = W[1] - sarr[1] + b0;                                              \
    W[3] = W[2] - sarr[2] + (b1 - b0);                                       \
}

__global__ __launch_bounds__(256) void ssim_kernel(
    const float* __restrict__ ws, float* __restrict__ out,
    int ch0, int nch)
{
    const int tid  = threadIdx.x;
    const int wid  = blockIdx.x * 4 + (tid >> 6);
    const int lane = tid & 63;
    const int total = nch * BANDS * NCHUNKS_R;
    if (wid >= total) return;

    const int cg    = wid / (BANDS * NCHUNKS_R);
    const int rem   = wid - cg * (BANDS * NCHUNKS_R);
    const int band  = rem / NCHUNKS_R;
    const int chunk = rem - band * NCHUNKS_R;

    const int t0 = 3 + chunk * ROWS_PW;
    const int t1 = min(t0 + ROWS_PW, T_FRAMES - 3);   // 398

    const int cb = band * BAND_ADV;
    int c4 = cb + 4 * lane;
    if (c4 > 1024) c4 = 1024;      // stay inside the 1028-float row (no OOB)

    const size_t perT = (size_t)T_FRAMES * F_STRIDE;
    const float* __restrict__ X = ws + SPEC_OFF + (size_t)cg * perT + c4;
    const float* __restrict__ Y = ws + SPEC_OFF + ((size_t)nch + cg) * perT + c4;

    const int  fo      = cb + 3 + 4 * lane;   // first output col of this lane
    const bool lane_ok = (lane <= 61);
    const float inv49  = 1.0f / 49.0f;

    float sx[4] = {0,0,0,0}, sy[4] = {0,0,0,0}, sxx[4] = {0,0,0,0},
          syy[4] = {0,0,0,0}, sxy[4] = {0,0,0,0};

    // vertical warmup: rows [t0-3, t0+2]
    for (int rr = t0 - 3; rr < t0 + 3; ++rr) {
        float4 xv = *(const float4*)(X + (size_t)rr * F_STRIDE);
        float4 yv = *(const float4*)(Y + (size_t)rr * F_STRIDE);
        float xa[4] = {xv.x, xv.y, xv.z, xv.w}, ya[4] = {yv.x, yv.y, yv.z, yv.w};
        #pragma unroll
        for (int c = 0; c < 4; ++c) {
            sx[c] += xa[c]; sy[c] += ya[c];
            sxx[c] += xa[c]*xa[c]; syy[c] += ya[c]*ya[c]; sxy[c] += xa[c]*ya[c];
        }
    }

    double acc = 0.0;

    #pragma unroll 1
    for (int t = t0; t < t1; ++t) {
        {   // add row t+3
            float4 xv = *(const float4*)(X + (size_t)(t + 3) * F_STRIDE);
            float4 yv = *(const float4*)(Y + (size_t)(t + 3) * F_STRIDE);
            float xa[4] = {xv.x, xv.y, xv.z, xv.w}, ya[4] = {yv.x, yv.y, yv.z, yv.w};
            #pragma unroll
            for (int c = 0; c < 4; ++c) {
                sx[c] += xa[c]; sy[c] += ya[c];
                sxx[c] += xa[c]*xa[c]; syy[c] += ya[c]*ya[c]; sxy[c] += xa[c]*ya[c];
            }
        }

        // horizontal 7-windows from lane prefixes + neighbor shuffles
        float wx[4], wy[4], wxx[4], wyy[4], wxy[4];
        HWIN7(sx,  wx);
        HWIN7(sy,  wy);
        HWIN7(sxx, wxx);
        HWIN7(syy, wyy);
        HWIN7(sxy, wxy);

        #pragma unroll
        for (int c = 0; c < 4; ++c) {
            if (lane_ok && (fo + c <= 1021)) {
                float ux  = wx[c]  * inv49, uy  = wy[c]  * inv49;
                float uxx = wxx[c] * inv49, uyy = wyy[c] * inv49, uxy = wxy[c] * inv49;
                float vx  = COV_NORM_ * (uxx - ux * ux);
                float vy  = COV_NORM_ * (uyy - uy * uy);
                float vxy = COV_NORM_ * (uxy - ux * uy);
                float Sv = ((2.f * ux * uy + C1_) * (2.f * vxy + C2_)) /
                           ((ux * ux + uy * uy + C1_) * (vx + vy + C2_));
                acc += (double)Sv;
            }
        }

        {   // subtract row t-3
            float4 xv = *(const float4*)(X + (size_t)(t - 3) * F_STRIDE);
            float4 yv = *(const float4*)(Y + (size_t)(t - 3) * F_STRIDE);
            float xa[4] = {xv.x, xv.y, xv.z, xv.w}, ya[4] = {yv.x, yv.y, yv.z, yv.w};
            #pragma unroll
            for (int c = 0; c < 4; ++c) {
                sx[c] -= xa[c]; sy[c] -= ya[c];
                sxx[c] -= xa[c]*xa[c]; syy[c] -= ya[c]*ya[c]; sxy[c] -= xa[c]*ya[c];
            }
        }
    }

    // wave-level reduction, one atomic per wave
    #pragma unroll
    for (int off = 32; off > 0; off >>= 1) acc += __shfl_down(acc, off, 64);
    if (lane == 0) {
        atomicAdd(&out[ch0 + cg], (float)(acc / (395.0 * 1019.0)));
    }
}

extern "C" void kernel_launch(void* const* d_in, const int* in_sizes, int n_in,
                              void* d_out, int out_size, void* d_ws, size_t ws_size,
                              hipStream_t stream) {
    const float* x0 = (const float*)d_in[0];   // output
    const float* x1 = (const float*)d_in[1];   // target
    float* out = (float*)d_out;
    float* ws  = (float*)d_ws;

    const size_t table_bytes  = (size_t)SPEC_OFF * sizeof(float);
    const size_t per_ch_bytes = (size_t)2 * T_FRAMES * F_STRIDE * sizeof(float);
    int G = (int)((ws_size - table_bytes) / per_ch_bytes);
    if (G > N_CH) G = N_CH;
    if (G < 1)    G = 1;

    init_tables_kernel<<<dim3(16), dim3(256), 0, stream>>>(ws, out);

    for (int ch0 = 0; ch0 < N_CH; ch0 += G) {
        const int nch = (N_CH - ch0 < G) ? (N_CH - ch0) : G;

        if (nch == 64) {
            stft_mag_kernel<<<dim3(T_FRAMES * 64), dim3(256), 0, stream>>>(x0, x1, ws, ch0, nch, 1);
        } else {
            stft_mag_kernel<<<dim3(T_FRAMES, nch), dim3(256), 0, stream>>>(x0, x1, ws, ch0, nch, 0);
        }

        const int nwaves = nch * BANDS * NCHUNKS_R;
        ssim_kernel<<<dim3((nwaves + 3) / 4), dim3(256), 0, stream>>>(ws, out, ch0, nch);
    }
}

// Round 4
// 361.965 us; speedup vs baseline: 1.0243x; 1.0243x over previous
//
#include <hip/hip_runtime.h>
#include <math.h>

#ifndef M_PI
#define M_PI 3.14159265358979323846
#endif

constexpr int S_LEN    = 176400;
constexpr int NFFT     = 2048;
constexpr int NC       = 1024;
constexpr int HOP_     = 441;
constexpr int T_FRAMES = 401;
constexpr int F_BINS   = 1025;
constexpr int F_STRIDE = 1028;     // fp32 spec row stride (16B aligned)
constexpr int N_CH     = 64;
constexpr float EPS_   = 1e-8f;
constexpr float C1_    = 0.0004f;
constexpr float C2_    = 0.0036f;
constexpr float COV_NORM_ = 49.0f / 48.0f;

// workspace float offsets
constexpr int WIN_OFF  = 0;        // float[2048] hann window
constexpr int TWG_OFF  = 2048;     // float2[768]  tw[e] = exp(-2pi i e/1024)
constexpr int UTW_OFF  = 3584;     // float2[1025] exp(-i pi r/1024)
constexpr int SPEC_OFF = 5696;

// ssim wave decomposition: 5 column bands x 25 row chunks per channel
constexpr int ROWS_PW   = 16;
constexpr int NCHUNKS_R = 25;      // ceil(395/16)
constexpr int BANDS     = 5;
constexpr int BAND_ADV  = 248;     // 62 producing lanes * 4 cols

// LDS bank swizzle: phys(i) = i ^ ((i>>2)&15) ^ ((i>>6)&15).
// Triangular in GF(2) (bits0-3 ^= f(bits2-9)) -> bijective on [0,1024).
// Conflict-checked per pattern (16 consecutive lanes -> 16 distinct low-nibbles).
__device__ __forceinline__ int phys(int i) { return i ^ ((i >> 2) & 15) ^ ((i >> 6) & 15); }

__device__ __forceinline__ float2 cadd(float2 a, float2 b){ return make_float2(a.x+b.x, a.y+b.y); }
__device__ __forceinline__ float2 csub(float2 a, float2 b){ return make_float2(a.x-b.x, a.y-b.y); }
__device__ __forceinline__ float2 cmul(float2 a, float2 b){ return make_float2(a.x*b.x-a.y*b.y, a.x*b.y+a.y*b.x); }

__global__ __launch_bounds__(256) void init_tables_kernel(float* __restrict__ ws, float* __restrict__ out) {
    const int idx = blockIdx.x * 256 + threadIdx.x;
    if (idx < 64) out[idx] = 0.0f;
    if (idx < NFFT) {
        ws[WIN_OFF + idx] = 0.5f - 0.5f * cosf((float)(2.0 * M_PI / NFFT) * (float)idx);
    }
    if (idx < 768) {
        float ang = -2.0f * (float)M_PI * (float)idx / (float)NC;
        float s, c; sincosf(ang, &s, &c);
        ws[TWG_OFF + 2*idx] = c; ws[TWG_OFF + 2*idx+1] = s;
    }
    if (idx < F_BINS) {
        float ang = -(float)M_PI * (float)idx / (float)NC;
        float s, c; sincosf(ang, &s, &c);
        ws[UTW_OFF + 2*idx] = c; ws[UTW_OFF + 2*idx+1] = s;
    }
}

// In-place radix-4 DIF butterfly: reads 4 LDS slots, writes SAME 4 slots.
__device__ __forceinline__ void r4_dif_inplace(
    float2* __restrict__ A, int r0, int r1, int r2, int r3,
    float2 w1, float2 w2, float2 w3, bool tw)
{
    float2 x0c = A[r0];
    float2 x1c = A[r1];
    float2 x2c = A[r2];
    float2 x3c = A[r3];

    float2 a = cadd(x0c, x2c);
    float2 b = csub(x0c, x2c);
    float2 c = cadd(x1c, x3c);
    float2 d = csub(x1c, x3c);

    float2 y0 = cadd(a, c);
    float2 y2 = csub(a, c);
    float2 y1 = make_float2(b.x + d.y, b.y - d.x);   // b - i*d
    float2 y3 = make_float2(b.x - d.y, b.y + d.x);   // b + i*d

    A[r0] = y0;
    A[r1] = tw ? cmul(y1, w1) : y1;
    A[r2] = tw ? cmul(y2, w2) : y2;
    A[r3] = tw ? cmul(y3, w3) : y3;
}

// Block-wide DUAL 1024-pt complex radix-4 IN-PLACE DIF (unchanged from R2:
// 194.8us, VALU 77%, occ 81%).
__global__ __launch_bounds__(256, 8) void stft_mag_kernel(
    const float* __restrict__ x0, const float* __restrict__ x1,
    float* __restrict__ ws, int ch0, int nch, int swizzle)
{
    __shared__ float2 buf[2 * NC];   // FFT0 at [0,NC), FFT1 at [NC,2NC)

    const int tid = threadIdx.x;

    int ch, t;
    if (swizzle) {
        int g = blockIdx.x;
        ch = ch0 + (g & 7) * 8 + ((g >> 3) & 7);
        t  = g >> 6;
    } else {
        t  = blockIdx.x;
        ch = ch0 + blockIdx.y;
    }

    const float* __restrict__ xin0 = x0 + (size_t)ch * S_LEN;
    const float* __restrict__ xin1 = x1 + (size_t)ch * S_LEN;
    const float*  __restrict__ win = ws + WIN_OFF;
    const float2* __restrict__ twg = (const float2*)(ws + TWG_OFF);
    const float2* __restrict__ utw = (const float2*)(ws + UTW_OFF);

    // ---- pack: flat float index n over [0,2048); complex ci = n>>1 (swizzled)
    const int base = t * HOP_ - NFFT / 2;
    float* fA0 = (float*)buf;             // FFT0
    float* fA1 = (float*)(buf + NC);      // FFT1 (+8 KB)
    if (base >= 0 && base + NFFT <= S_LEN) {
        #pragma unroll
        for (int k = 0; k < NFFT / 256; ++k) {
            int n = k * 256 + tid;
            int j = base + n;
            float w = win[n];
            int p = 2 * phys(n >> 1) + (n & 1);
            fA0[p] = xin0[j] * w;
            fA1[p] = xin1[j] * w;
        }
    } else {
        #pragma unroll
        for (int k = 0; k < NFFT / 256; ++k) {
            int n = k * 256 + tid;
            int j = base + n;
            j = (j < 0) ? -j : j;
            j = (j >= S_LEN) ? (2 * S_LEN - 2 - j) : j;
            float w = win[n];
            int p = 2 * phys(n >> 1) + (n & 1);
            fA0[p] = xin0[j] * w;
            fA1[p] = xin1[j] * w;
        }
    }
    __syncthreads();

    // ---- 5-stage in-place radix-4 DIF, x2 FFTs
    #pragma unroll
    for (int s = 0; s < 5; ++s) {
        const int M  = 256 >> (2 * s);
        const int q  = tid & (M - 1);
        const int e  = q << (2 * s);
        const int i0 = 4 * (tid - q) + q;

        const int r0 = phys(i0);
        const int r1 = phys(i0 + M);
        const int r2 = phys(i0 + 2 * M);
        const int r3 = phys(i0 + 3 * M);

        float2 w1, w2, w3;
        if (s < 4) {
            w1 = twg[e];
            w2 = twg[2 * e];
            w3 = twg[3 * e];
        } else {
            w1 = w2 = w3 = make_float2(1.0f, 0.0f);
        }

        r4_dif_inplace(buf,      r0, r1, r2, r3, w1, w2, w3, s < 4);
        r4_dif_inplace(buf + NC, r0, r1, r2, r3, w1, w2, w3, s < 4);

        __syncthreads();
    }

    // ---- real-FFT unpack + magnitude + fp32 coalesced stores (both tensors)
    const size_t perT = (size_t)T_FRAMES * F_STRIDE;
    float* __restrict__ sout0 =
        ws + SPEC_OFF + (size_t)(ch - ch0) * perT + (size_t)t * F_STRIDE;
    float* __restrict__ sout1 = sout0 + (size_t)nch * perT;

    const int R8 = ((tid & 3) << 6) | ((tid & 12) << 2) | ((tid >> 2) & 12) | ((tid >> 6) & 3);

    #pragma unroll
    for (int k = 0; k < 5; ++k) {
        int r = k * 256 + tid;
        if (k < 4 || tid == 0) {
            const int ra = (k < 4) ? ((R8 << 2) | k) : 0;          // rev4(r & 1023)
            const int rn = (NC - r) & (NC - 1);
            const int rb = ((rn & 3) << 8) | ((rn & 12) << 4) | (rn & 48)
                         | ((rn >> 4) & 12) | ((rn >> 8) & 3);     // rev4(rn)
            const int ia = phys(ra);
            const int ib = phys(rb);
            float2 wu = utw[r];

            {   // tensor 0
                float2 Zr = buf[ia];
                float2 Zn = buf[ib];
                float Ex = 0.5f * (Zr.x + Zn.x);
                float Ey = 0.5f * (Zr.y - Zn.y);
                float Ox = 0.5f * (Zr.y + Zn.y);
                float Oy = 0.5f * (Zn.x - Zr.x);
                float Xx = Ex + wu.x * Ox - wu.y * Oy;
                float Xy = Ey + wu.x * Oy + wu.y * Ox;
                sout0[r] = sqrtf(fmaxf(Xx * Xx + Xy * Xy, EPS_));
            }
            {   // tensor 1
                float2 Zr = buf[NC + ia];
                float2 Zn = buf[NC + ib];
                float Ex = 0.5f * (Zr.x + Zn.x);
                float Ey = 0.5f * (Zr.y - Zn.y);
                float Ox = 0.5f * (Zr.y + Zn.y);
                float Oy = 0.5f * (Zn.x - Zr.x);
                float Xx = Ex + wu.x * Ox - wu.y * Oy;
                float Xy = Ey + wu.x * Oy + wu.y * Ox;
                sout1[r] = sqrtf(fmaxf(Xx * Xx + Xy * Xy, EPS_));
            }
        }
    }
}

// SSIM v2.1: barrier-free, LDS-free, wave-independent, with ONE-ITERATION-
// AHEAD register prefetch (the R2 latency-hiding pattern v2 dropped).
// Each 64-lane wave owns (channel, column-band, row-chunk).  Lane L holds the
// vertical rolling 7-row sums of 4 columns in registers; the horizontal 7-wide
// window is assembled from per-lane prefix sums + neighbor-lane prefixes via
// __shfl_down (+1, +2 lanes).  While row t is processed, the add-row (t+4)
// and sub-row (t-2) for the NEXT iteration are already in flight (clamped
// always-load, no branch), so L2/LLC latency hides under the shuffle+SSIM
// math instead of serializing with it.
#define HWIN7(sarr, W) {                                                     \
    float p0 = sarr[0], p01 = p0 + sarr[1], p012 = p01 + sarr[2],            \
          P = p012 + sarr[3];                                                \
    float a1 = __shfl_down(p012, 1, 64);                                     \
    float A1 = __shfl_down(P,    1, 64);                                     \
    float b0 = __shfl_down(p0,   2, 64);                                     \
    float b1 = __shfl_down(p01,  2, 64);                                     \
    W[0] = P + a1;                                                           \
    W[1] = P - p0 + A1;                                                      \
    W[2] = W[1] - sarr[1] + b0;                                              \
    W[3] = W[2] - sarr[2] + (b1 - b0);                                       \
}

__global__ __launch_bounds__(256) void ssim_kernel(
    const float* __restrict__ ws, float* __restrict__ out,
    int ch0, int nch)
{
    const int tid  = threadIdx.x;
    const int wid  = blockIdx.x * 4 + (tid >> 6);
    const int lane = tid & 63;
    const int total = nch * BANDS * NCHUNKS_R;
    if (wid >= total) return;

    const int cg    = wid / (BANDS * NCHUNKS_R);
    const int rem   = wid - cg * (BANDS * NCHUNKS_R);
    const int band  = rem / NCHUNKS_R;
    const int chunk = rem - band * NCHUNKS_R;

    const int t0 = 3 + chunk * ROWS_PW;
    const int t1 = min(t0 + ROWS_PW, T_FRAMES - 3);   // 398

    const int cb = band * BAND_ADV;
    int c4 = cb + 4 * lane;
    if (c4 > 1024) c4 = 1024;      // stay inside the 1028-float row (no OOB)

    const size_t perT = (size_t)T_FRAMES * F_STRIDE;
    const float* __restrict__ X = ws + SPEC_OFF + (size_t)cg * perT + c4;
    const float* __restrict__ Y = ws + SPEC_OFF + ((size_t)nch + cg) * perT + c4;

    const int  fo      = cb + 3 + 4 * lane;   // first output col of this lane
    const bool lane_ok = (lane <= 61);
    const float inv49  = 1.0f / 49.0f;

    float sx[4] = {0,0,0,0}, sy[4] = {0,0,0,0}, sxx[4] = {0,0,0,0},
          syy[4] = {0,0,0,0}, sxy[4] = {0,0,0,0};

    // vertical warmup: rows [t0-3, t0+2] (12 independent loads, all in flight)
    for (int rr = t0 - 3; rr < t0 + 3; ++rr) {
        float4 xv = *(const float4*)(X + (size_t)rr * F_STRIDE);
        float4 yv = *(const float4*)(Y + (size_t)rr * F_STRIDE);
        float xa[4] = {xv.x, xv.y, xv.z, xv.w}, ya[4] = {yv.x, yv.y, yv.z, yv.w};
        #pragma unroll
        for (int c = 0; c < 4; ++c) {
            sx[c] += xa[c]; sy[c] += ya[c];
            sxx[c] += xa[c]*xa[c]; syy[c] += ya[c]*ya[c]; sxy[c] += xa[c]*ya[c];
        }
    }

    // prologue: current add-row (t0+3) and sub-row (t0-3)
    float4 cxa = *(const float4*)(X + (size_t)(t0 + 3) * F_STRIDE);
    float4 cya = *(const float4*)(Y + (size_t)(t0 + 3) * F_STRIDE);
    float4 cxs = *(const float4*)(X + (size_t)(t0 - 3) * F_STRIDE);
    float4 cys = *(const float4*)(Y + (size_t)(t0 - 3) * F_STRIDE);

    double acc = 0.0;

    #pragma unroll 1
    for (int t = t0; t < t1; ++t) {
        // issue NEXT iteration's loads first (independent of everything below;
        // clamped row index -> last iteration harmlessly re-loads row <=400)
        const int tn_a = min(t + 4, T_FRAMES - 1);
        const int tn_s = t - 2;                      // >= 1, always valid
        float4 nxa = *(const float4*)(X + (size_t)tn_a * F_STRIDE);
        float4 nya = *(const float4*)(Y + (size_t)tn_a * F_STRIDE);
        float4 nxs = *(const float4*)(X + (size_t)tn_s * F_STRIDE);
        float4 nys = *(const float4*)(Y + (size_t)tn_s * F_STRIDE);

        {   // add row t+3 (prefetched last iteration)
            float xa[4] = {cxa.x, cxa.y, cxa.z, cxa.w}, ya[4] = {cya.x, cya.y, cya.z, cya.w};
            #pragma unroll
            for (int c = 0; c < 4; ++c) {
                sx[c] += xa[c]; sy[c] += ya[c];
                sxx[c] += xa[c]*xa[c]; syy[c] += ya[c]*ya[c]; sxy[c] += xa[c]*ya[c];
            }
        }

        // horizontal 7-windows from lane prefixes + neighbor shuffles
        float wx[4], wy[4], wxx[4], wyy[4], wxy[4];
        HWIN7(sx,  wx);
        HWIN7(sy,  wy);
        HWIN7(sxx, wxx);
        HWIN7(syy, wyy);
        HWIN7(sxy, wxy);

        #pragma unroll
        for (int c = 0; c < 4; ++c) {
            if (lane_ok && (fo + c <= 1021)) {
                float ux  = wx[c]  * inv49, uy  = wy[c]  * inv49;
                float uxx = wxx[c] * inv49, uyy = wyy[c] * inv49, uxy = wxy[c] * inv49;
                float vx  = COV_NORM_ * (uxx - ux * ux);
                float vy  = COV_NORM_ * (uyy - uy * uy);
                float vxy = COV_NORM_ * (uxy - ux * uy);
                float Sv = ((2.f * ux * uy + C1_) * (2.f * vxy + C2_)) /
                           ((ux * ux + uy * uy + C1_) * (vx + vy + C2_));
                acc += (double)Sv;
            }
        }

        {   // subtract row t-3 (prefetched last iteration)
            float xa[4] = {cxs.x, cxs.y, cxs.z, cxs.w}, ya[4] = {cys.x, cys.y, cys.z, cys.w};
            #pragma unroll
            for (int c = 0; c < 4; ++c) {
                sx[c] -= xa[c]; sy[c] -= ya[c];
                sxx[c] -= xa[c]*xa[c]; syy[c] -= ya[c]*ya[c]; sxy[c] -= xa[c]*ya[c];
            }
        }

        // rotate prefetch registers
        cxa = nxa; cya = nya; cxs = nxs; cys = nys;
    }

    // wave-level reduction, one atomic per wave
    #pragma unroll
    for (int off = 32; off > 0; off >>= 1) acc += __shfl_down(acc, off, 64);
    if (lane == 0) {
        atomicAdd(&out[ch0 + cg], (float)(acc / (395.0 * 1019.0)));
    }
}

extern "C" void kernel_launch(void* const* d_in, const int* in_sizes, int n_in,
                              void* d_out, int out_size, void* d_ws, size_t ws_size,
                              hipStream_t stream) {
    const float* x0 = (const float*)d_in[0];   // output
    const float* x1 = (const float*)d_in[1];   // target
    float* out = (float*)d_out;
    float* ws  = (float*)d_ws;

    const size_t table_bytes  = (size_t)SPEC_OFF * sizeof(float);
    const size_t per_ch_bytes = (size_t)2 * T_FRAMES * F_STRIDE * sizeof(float);
    int G = (int)((ws_size - table_bytes) / per_ch_bytes);
    if (G > N_CH) G = N_CH;
    if (G < 1)    G = 1;

    init_tables_kernel<<<dim3(16), dim3(256), 0, stream>>>(ws, out);

    for (int ch0 = 0; ch0 < N_CH; ch0 += G) {
        const int nch = (N_CH - ch0 < G) ? (N_CH - ch0) : G;

        if (nch == 64) {
            stft_mag_kernel<<<dim3(T_FRAMES * 64), dim3(256), 0, stream>>>(x0, x1, ws, ch0, nch, 1);
        } else {
            stft_mag_kernel<<<dim3(T_FRAMES, nch), dim3(256), 0, stream>>>(x0, x1, ws, ch0, nch, 0);
        }

        const int nwaves = nch * BANDS * NCHUNKS_R;
        ssim_kernel<<<dim3((nwaves + 3) / 4), dim3(256), 0, stream>>>(ws, out, ch0, nch);
    }
}

// Round 5
// 344.096 us; speedup vs baseline: 1.0775x; 1.0519x over previous
//
#include <hip/hip_runtime.h>
#include <math.h>

#ifndef M_PI
#define M_PI 3.14159265358979323846
#endif

constexpr int S_LEN    = 176400;
constexpr int NFFT     = 2048;
constexpr int NC       = 1024;
constexpr int HOP_     = 441;
constexpr int T_FRAMES = 401;
constexpr int F_BINS   = 1025;
constexpr int F_STRIDE = 1028;     // fp32 spec row stride (16B aligned)
constexpr int N_CH     = 64;
constexpr float EPS_   = 1e-8f;
constexpr float C1_    = 0.0004f;
constexpr float C2_    = 0.0036f;
constexpr float COV_NORM_ = 49.0f / 48.0f;

// workspace float offsets
constexpr int WIN_OFF  = 0;        // float[2048] hann window
constexpr int TWG_OFF  = 2048;     // float2[768]  tw[e] = exp(-2pi i e/1024)
constexpr int UTW_OFF  = 3584;     // float2[1025] exp(-i pi r/1024)
constexpr int SPEC_OFF = 5696;

// ssim wave decomposition: 5 column bands x 17 row chunks per channel
constexpr int ROWS_PW   = 24;
constexpr int NCHUNKS_R = 17;      // ceil(395/24)
constexpr int BANDS     = 5;
constexpr int BAND_ADV  = 248;     // 62 producing lanes * 4 cols

// LDS bank swizzle: phys(i) = i ^ ((i>>2)&15) ^ ((i>>6)&15).
// Triangular in GF(2) (bits0-3 ^= f(bits2-9)) -> bijective on [0,1024).
// Conflict-checked per pattern (16 consecutive lanes -> 16 distinct low-nibbles).
__device__ __forceinline__ int phys(int i) { return i ^ ((i >> 2) & 15) ^ ((i >> 6) & 15); }

__device__ __forceinline__ float2 cadd(float2 a, float2 b){ return make_float2(a.x+b.x, a.y+b.y); }
__device__ __forceinline__ float2 csub(float2 a, float2 b){ return make_float2(a.x-b.x, a.y-b.y); }
__device__ __forceinline__ float2 cmul(float2 a, float2 b){ return make_float2(a.x*b.x-a.y*b.y, a.x*b.y+a.y*b.x); }

__global__ __launch_bounds__(256) void init_tables_kernel(float* __restrict__ ws, float* __restrict__ out) {
    const int idx = blockIdx.x * 256 + threadIdx.x;
    if (idx < 64) out[idx] = 0.0f;
    if (idx < NFFT) {
        ws[WIN_OFF + idx] = 0.5f - 0.5f * cosf((float)(2.0 * M_PI / NFFT) * (float)idx);
    }
    if (idx < 768) {
        float ang = -2.0f * (float)M_PI * (float)idx / (float)NC;
        float s, c; sincosf(ang, &s, &c);
        ws[TWG_OFF + 2*idx] = c; ws[TWG_OFF + 2*idx+1] = s;
    }
    if (idx < F_BINS) {
        float ang = -(float)M_PI * (float)idx / (float)NC;
        float s, c; sincosf(ang, &s, &c);
        ws[UTW_OFF + 2*idx] = c; ws[UTW_OFF + 2*idx+1] = s;
    }
}

// In-place radix-4 DIF butterfly: reads 4 LDS slots, writes SAME 4 slots.
__device__ __forceinline__ void r4_dif_inplace(
    float2* __restrict__ A, int r0, int r1, int r2, int r3,
    float2 w1, float2 w2, float2 w3, bool tw)
{
    float2 x0c = A[r0];
    float2 x1c = A[r1];
    float2 x2c = A[r2];
    float2 x3c = A[r3];

    float2 a = cadd(x0c, x2c);
    float2 b = csub(x0c, x2c);
    float2 c = cadd(x1c, x3c);
    float2 d = csub(x1c, x3c);

    float2 y0 = cadd(a, c);
    float2 y2 = csub(a, c);
    float2 y1 = make_float2(b.x + d.y, b.y - d.x);   // b - i*d
    float2 y3 = make_float2(b.x - d.y, b.y + d.x);   // b + i*d

    A[r0] = y0;
    A[r1] = tw ? cmul(y1, w1) : y1;
    A[r2] = tw ? cmul(y2, w2) : y2;
    A[r3] = tw ? cmul(y3, w3) : y3;
}

// Block-wide DUAL 1024-pt complex radix-4 IN-PLACE DIF (unchanged from R2:
// ~191us, VALU ~80%, occ ~81%).
__global__ __launch_bounds__(256, 8) void stft_mag_kernel(
    const float* __restrict__ x0, const float* __restrict__ x1,
    float* __restrict__ ws, int ch0, int nch, int swizzle)
{
    __shared__ float2 buf[2 * NC];   // FFT0 at [0,NC), FFT1 at [NC,2NC)

    const int tid = threadIdx.x;

    int ch, t;
    if (swizzle) {
        int g = blockIdx.x;
        ch = ch0 + (g & 7) * 8 + ((g >> 3) & 7);
        t  = g >> 6;
    } else {
        t  = blockIdx.x;
        ch = ch0 + blockIdx.y;
    }

    const float* __restrict__ xin0 = x0 + (size_t)ch * S_LEN;
    const float* __restrict__ xin1 = x1 + (size_t)ch * S_LEN;
    const float*  __restrict__ win = ws + WIN_OFF;
    const float2* __restrict__ twg = (const float2*)(ws + TWG_OFF);
    const float2* __restrict__ utw = (const float2*)(ws + UTW_OFF);

    // ---- pack: flat float index n over [0,2048); complex ci = n>>1 (swizzled)
    const int base = t * HOP_ - NFFT / 2;
    float* fA0 = (float*)buf;             // FFT0
    float* fA1 = (float*)(buf + NC);      // FFT1 (+8 KB)
    if (base >= 0 && base + NFFT <= S_LEN) {
        #pragma unroll
        for (int k = 0; k < NFFT / 256; ++k) {
            int n = k * 256 + tid;
            int j = base + n;
            float w = win[n];
            int p = 2 * phys(n >> 1) + (n & 1);
            fA0[p] = xin0[j] * w;
            fA1[p] = xin1[j] * w;
        }
    } else {
        #pragma unroll
        for (int k = 0; k < NFFT / 256; ++k) {
            int n = k * 256 + tid;
            int j = base + n;
            j = (j < 0) ? -j : j;
            j = (j >= S_LEN) ? (2 * S_LEN - 2 - j) : j;
            float w = win[n];
            int p = 2 * phys(n >> 1) + (n & 1);
            fA0[p] = xin0[j] * w;
            fA1[p] = xin1[j] * w;
        }
    }
    __syncthreads();

    // ---- 5-stage in-place radix-4 DIF, x2 FFTs
    #pragma unroll
    for (int s = 0; s < 5; ++s) {
        const int M  = 256 >> (2 * s);
        const int q  = tid & (M - 1);
        const int e  = q << (2 * s);
        const int i0 = 4 * (tid - q) + q;

        const int r0 = phys(i0);
        const int r1 = phys(i0 + M);
        const int r2 = phys(i0 + 2 * M);
        const int r3 = phys(i0 + 3 * M);

        float2 w1, w2, w3;
        if (s < 4) {
            w1 = twg[e];
            w2 = twg[2 * e];
            w3 = twg[3 * e];
        } else {
            w1 = w2 = w3 = make_float2(1.0f, 0.0f);
        }

        r4_dif_inplace(buf,      r0, r1, r2, r3, w1, w2, w3, s < 4);
        r4_dif_inplace(buf + NC, r0, r1, r2, r3, w1, w2, w3, s < 4);

        __syncthreads();
    }

    // ---- real-FFT unpack + magnitude + fp32 coalesced stores (both tensors)
    const size_t perT = (size_t)T_FRAMES * F_STRIDE;
    float* __restrict__ sout0 =
        ws + SPEC_OFF + (size_t)(ch - ch0) * perT + (size_t)t * F_STRIDE;
    float* __restrict__ sout1 = sout0 + (size_t)nch * perT;

    const int R8 = ((tid & 3) << 6) | ((tid & 12) << 2) | ((tid >> 2) & 12) | ((tid >> 6) & 3);

    #pragma unroll
    for (int k = 0; k < 5; ++k) {
        int r = k * 256 + tid;
        if (k < 4 || tid == 0) {
            const int ra = (k < 4) ? ((R8 << 2) | k) : 0;          // rev4(r & 1023)
            const int rn = (NC - r) & (NC - 1);
            const int rb = ((rn & 3) << 8) | ((rn & 12) << 4) | (rn & 48)
                         | ((rn >> 4) & 12) | ((rn >> 8) & 3);     // rev4(rn)
            const int ia = phys(ra);
            const int ib = phys(rb);
            float2 wu = utw[r];

            {   // tensor 0
                float2 Zr = buf[ia];
                float2 Zn = buf[ib];
                float Ex = 0.5f * (Zr.x + Zn.x);
                float Ey = 0.5f * (Zr.y - Zn.y);
                float Ox = 0.5f * (Zr.y + Zn.y);
                float Oy = 0.5f * (Zn.x - Zr.x);
                float Xx = Ex + wu.x * Ox - wu.y * Oy;
                float Xy = Ey + wu.x * Oy + wu.y * Ox;
                sout0[r] = sqrtf(fmaxf(Xx * Xx + Xy * Xy, EPS_));
            }
            {   // tensor 1
                float2 Zr = buf[NC + ia];
                float2 Zn = buf[NC + ib];
                float Ex = 0.5f * (Zr.x + Zn.x);
                float Ey = 0.5f * (Zr.y - Zn.y);
                float Ox = 0.5f * (Zr.y + Zn.y);
                float Oy = 0.5f * (Zn.x - Zr.x);
                float Xx = Ex + wu.x * Ox - wu.y * Oy;
                float Xy = Ey + wu.x * Oy + wu.y * Ox;
                sout1[r] = sqrtf(fmaxf(Xx * Xx + Xy * Xy, EPS_));
            }
        }
    }
}

// SSIM v3: read-once 6-row REGISTER RING (halves memory traffic vs v2).
// Evidence: v2-block(532MB)=147us vs v2-wave(640MB)=172us -> dur scales with
// bytes => throughput-bound on the spec read path.  So each (x,y) row pair is
// now loaded ONCE; the sliding-window subtract re-derives xx/yy/xy from the
// ring (3 fma/col) instead of re-loading the row.  Ring indices are
// compile-time (inner 6-unroll, slot=j) so the ring stays in VGPRs.
// Wave owns (channel, band, 24-row chunk); horizontal 7-window via lane
// prefixes + __shfl_down as in v2.
#define HWIN7(sarr, W) {                                                     \
    float p0 = sarr[0], p01 = p0 + sarr[1], p012 = p01 + sarr[2],            \
          P = p012 + sarr[3];                                                \
    float a1 = __shfl_down(p012, 1, 64);                                     \
    float A1 = __shfl_down(P,    1, 64);                                     \
    float b0 = __shfl_down(p0,   2, 64);                                     \
    float b1 = __shfl_down(p01,  2, 64);                                     \
    W[0] = P + a1;                                                           \
    W[1] = P - p0 + A1;                                                      \
    W[2] = W[1] - sarr[1] + b0;                                              \
    W[3] = W[2] - sarr[2] + (b1 - b0);                                       \
}

__global__ __launch_bounds__(256) void ssim_kernel(
    const float* __restrict__ ws, float* __restrict__ out,
    int ch0, int nch)
{
    const int tid  = threadIdx.x;
    const int wid  = blockIdx.x * 4 + (tid >> 6);
    const int lane = tid & 63;
    const int total = nch * BANDS * NCHUNKS_R;
    if (wid >= total) return;

    const int cg    = wid / (BANDS * NCHUNKS_R);
    const int rem   = wid - cg * (BANDS * NCHUNKS_R);
    const int band  = rem / NCHUNKS_R;
    const int chunk = rem - band * NCHUNKS_R;

    const int t0 = 3 + chunk * ROWS_PW;
    const int t1 = min(t0 + ROWS_PW, T_FRAMES - 3);   // <= 398

    const int cb = band * BAND_ADV;
    int c4 = cb + 4 * lane;
    if (c4 > 1024) c4 = 1024;      // stay inside the 1028-float row (no OOB)

    const size_t perT = (size_t)T_FRAMES * F_STRIDE;
    const float* __restrict__ X = ws + SPEC_OFF + (size_t)cg * perT + c4;
    const float* __restrict__ Y = ws + SPEC_OFF + ((size_t)nch + cg) * perT + c4;

    const int  fo      = cb + 3 + 4 * lane;   // first output col of this lane
    const bool lane_ok = (lane <= 61);
    const float inv49  = 1.0f / 49.0f;

    float sx[4] = {0,0,0,0}, sy[4] = {0,0,0,0}, sxx[4] = {0,0,0,0},
          syy[4] = {0,0,0,0}, sxy[4] = {0,0,0,0};
    float rgx[6][4], rgy[6][4];    // ring of raw (x,y) rows t-3..t+2

    // warmup: rows [t0-3, t0+2] -> sums + ring slots 0..5 (static indices)
    #pragma unroll
    for (int w = 0; w < 6; ++w) {
        const int rr = t0 - 3 + w;
        float4 xv = *(const float4*)(X + (size_t)rr * F_STRIDE);
        float4 yv = *(const float4*)(Y + (size_t)rr * F_STRIDE);
        float xa[4] = {xv.x, xv.y, xv.z, xv.w}, ya[4] = {yv.x, yv.y, yv.z, yv.w};
        #pragma unroll
        for (int c = 0; c < 4; ++c) {
            sx[c] += xa[c]; sy[c] += ya[c];
            sxx[c] += xa[c]*xa[c]; syy[c] += ya[c]*ya[c]; sxy[c] += xa[c]*ya[c];
            rgx[w][c] = xa[c]; rgy[w][c] = ya[c];
        }
    }

    // prologue: current add-row (t0+3) in flight
    float4 cxa = *(const float4*)(X + (size_t)(t0 + 3) * F_STRIDE);
    float4 cya = *(const float4*)(Y + (size_t)(t0 + 3) * F_STRIDE);

    double acc = 0.0;

    // iteration i = t - t0; ring slot of row t-3 is (i mod 6); the freshly
    // added row t+3 overwrites the same slot.  tb advances by 6 so slot = j
    // is a compile-time constant inside the unrolled body.
    #pragma unroll 1
    for (int tb = t0; tb < t1; tb += 6) {
        #pragma unroll
        for (int j = 0; j < 6; ++j) {
            const int t = tb + j;
            // next iteration's row pair (clamped; dead iters load row <=400)
            const int tn = min(t + 4, T_FRAMES - 1);
            float4 nxa = *(const float4*)(X + (size_t)tn * F_STRIDE);
            float4 nya = *(const float4*)(Y + (size_t)tn * F_STRIDE);

            float xa[4] = {cxa.x, cxa.y, cxa.z, cxa.w};
            float ya[4] = {cya.x, cya.y, cya.z, cya.w};

            // add row t+3
            #pragma unroll
            for (int c = 0; c < 4; ++c) {
                sx[c] += xa[c]; sy[c] += ya[c];
                sxx[c] += xa[c]*xa[c]; syy[c] += ya[c]*ya[c]; sxy[c] += xa[c]*ya[c];
            }

            // horizontal 7-windows from lane prefixes + neighbor shuffles
            float wx[4], wy[4], wxx[4], wyy[4], wxy[4];
            HWIN7(sx,  wx);
            HWIN7(sy,  wy);
            HWIN7(sxx, wxx);
            HWIN7(syy, wyy);
            HWIN7(sxy, wxy);

            const bool live = (t < t1);
            #pragma unroll
            for (int c = 0; c < 4; ++c) {
                if (live && lane_ok && (fo + c <= 1021)) {
                    float ux  = wx[c]  * inv49, uy  = wy[c]  * inv49;
                    float uxx = wxx[c] * inv49, uyy = wyy[c] * inv49, uxy = wxy[c] * inv49;
                    float vx  = COV_NORM_ * (uxx - ux * ux);
                    float vy  = COV_NORM_ * (uyy - uy * uy);
                    float vxy = COV_NORM_ * (uxy - ux * uy);
                    float Sv = ((2.f * ux * uy + C1_) * (2.f * vxy + C2_)) /
                               ((ux * ux + uy * uy + C1_) * (vx + vy + C2_));
                    acc += (double)Sv;
                }
            }

            // subtract row t-3 from the ring (recompute squares: 3 fma/col),
            // then store row t+3 into the same slot
            #pragma unroll
            for (int c = 0; c < 4; ++c) {
                float bx_ = rgx[j][c], by_ = rgy[j][c];
                sx[c]  -= bx_;      sy[c]  -= by_;
                sxx[c] -= bx_*bx_;  syy[c] -= by_*by_;  sxy[c] -= bx_*by_;
                rgx[j][c] = xa[c];  rgy[j][c] = ya[c];
            }

            // rotate prefetch registers
            cxa = nxa; cya = nya;
        }
    }

    // wave-level reduction, one atomic per wave
    #pragma unroll
    for (int off = 32; off > 0; off >>= 1) acc += __shfl_down(acc, off, 64);
    if (lane == 0) {
        atomicAdd(&out[ch0 + cg], (float)(acc / (395.0 * 1019.0)));
    }
}

extern "C" void kernel_launch(void* const* d_in, const int* in_sizes, int n_in,
                              void* d_out, int out_size, void* d_ws, size_t ws_size,
                              hipStream_t stream) {
    const float* x0 = (const float*)d_in[0];   // output
    const float* x1 = (const float*)d_in[1];   // target
    float* out = (float*)d_out;
    float* ws  = (float*)d_ws;

    const size_t table_bytes  = (size_t)SPEC_OFF * sizeof(float);
    const size_t per_ch_bytes = (size_t)2 * T_FRAMES * F_STRIDE * sizeof(float);
    int G = (int)((ws_size - table_bytes) / per_ch_bytes);
    if (G > N_CH) G = N_CH;
    if (G < 1)    G = 1;

    init_tables_kernel<<<dim3(16), dim3(256), 0, stream>>>(ws, out);

    for (int ch0 = 0; ch0 < N_CH; ch0 += G) {
        const int nch = (N_CH - ch0 < G) ? (N_CH - ch0) : G;

        if (nch == 64) {
            stft_mag_kernel<<<dim3(T_FRAMES * 64), dim3(256), 0, stream>>>(x0, x1, ws, ch0, nch, 1);
        } else {
            stft_mag_kernel<<<dim3(T_FRAMES, nch), dim3(256), 0, stream>>>(x0, x1, ws, ch0, nch, 0);
        }

        const int nwaves = nch * BANDS * NCHUNKS_R;
        ssim_kernel<<<dim3((nwaves + 3) / 4), dim3(256), 0, stream>>>(ws, out, ch0, nch);
    }
}